// Round 9
// baseline (475.772 us; speedup 1.0000x reference)
//
#include <hip/hip_runtime.h>
#include <math.h>

namespace {
constexpr int kB = 256;
constexpr int kD = 128;
constexpr int kN = 500000;
constexpr int kKC = 2049;             // K + 1
constexpr int kNPair = kB * kKC;      // 524544
constexpr float kTInv = 1.0f / 0.07f;
constexpr float kMom = 0.5f;
constexpr int kRB = 256;              // reduction grid size
constexpr long long kM = (long long)kN * kD;    // 64,000,000 floats per bank
constexpr long long kTot = 2 * kM;
constexpr int kChunk = 2048;                    // elems per scan block
constexpr int kNB1 = (kN + kChunk - 1) / kChunk; // 245
constexpr int kLdsStride = 132;                 // 528 B row pitch (16B-aligned)
// fused7 geometry: 16-row segments; 3 producer waves + 1 consumer wave/block
constexpr int kSegRows = 16;
constexpr int kSegF4 = kSegRows * kD / 4;       // 512 float4 per segment
constexpr int kSegs = (int)(kTot / ((long long)kSegRows * kD)); // 62500 (exact)
constexpr int kSegsB1 = kSegs / 2;              // 31250 (bank boundary, exact)
constexpr int kSPB = 60;                        // segments per block
constexpr int kNIprod = kSPB / 3;               // 20 producing intervals
constexpr int kNI = kNIprod + 1;                // +1 drain interval
constexpr int kGrid7 = (kSegs + kSPB - 1) / kSPB; // 1042
}

// ---------- CSR setup: bucket pairs by row index ----------

__global__ __launch_bounds__(256) void zero2_kernel(int* __restrict__ A, int* __restrict__ cur)
{
    int i = blockIdx.x * 256 + threadIdx.x;
    if (i < kN) { A[i] = 0; cur[i] = 0; }
}

__global__ __launch_bounds__(256) void hist_kernel(const int* __restrict__ cidx, int* __restrict__ A)
{
    int i = blockIdx.x * 256 + threadIdx.x;
    if (i < kNPair) atomicAdd(&A[cidx[i]], 1);
}

__global__ __launch_bounds__(256) void scan1_kernel(const int* __restrict__ A, int* __restrict__ bsum)
{
    long long base = (long long)blockIdx.x * kChunk;
    int t = threadIdx.x;
    int s = 0;
    #pragma unroll
    for (int j = 0; j < 8; ++j) {
        long long i = base + t * 8 + j;
        if (i < kN) s += A[i];
    }
    __shared__ int lds[256];
    lds[t] = s; __syncthreads();
    for (int st = 128; st > 0; st >>= 1) {
        if (t < st) lds[t] += lds[t + st];
        __syncthreads();
    }
    if (t == 0) bsum[blockIdx.x] = lds[0];
}

__global__ __launch_bounds__(256) void scan2_kernel(
    const int* __restrict__ bsum, int* __restrict__ bpre, int* __restrict__ offs)
{
    int t = threadIdx.x;
    int v = (t < kNB1) ? bsum[t] : 0;
    __shared__ int lds[256];
    lds[t] = v; __syncthreads();
    for (int st = 1; st < 256; st <<= 1) {
        int add = (t >= st) ? lds[t - st] : 0;
        __syncthreads();
        lds[t] += add;
        __syncthreads();
    }
    if (t < kNB1) bpre[t] = lds[t] - v;       // exclusive
    if (t == kNB1 - 1) offs[kN] = lds[t];     // total = kNPair
}

__global__ __launch_bounds__(256) void scan3_kernel(
    const int* __restrict__ A, const int* __restrict__ bpre, int* __restrict__ offs)
{
    int t = threadIdx.x;
    long long base = (long long)blockIdx.x * kChunk;
    int c[8]; int s = 0;
    #pragma unroll
    for (int j = 0; j < 8; ++j) {
        long long i = base + t * 8 + j;
        c[j] = (i < kN) ? A[i] : 0;
        s += c[j];
    }
    __shared__ int lds[256];
    lds[t] = s; __syncthreads();
    for (int st = 1; st < 256; st <<= 1) {
        int add = (t >= st) ? lds[t - st] : 0;
        __syncthreads();
        lds[t] += add;
        __syncthreads();
    }
    int excl = lds[t] - s + bpre[blockIdx.x];
    #pragma unroll
    for (int j = 0; j < 8; ++j) {
        long long i = base + t * 8 + j;
        if (i < kN) { offs[i] = excl; excl += c[j]; }
    }
}

__global__ __launch_bounds__(256) void scatter_kernel(
    const int* __restrict__ cidx, const int* __restrict__ offs,
    int* __restrict__ cur, int* __restrict__ sorted)
{
    int p = blockIdx.x * 256 + threadIdx.x;
    if (p < kNPair) {
        int r = cidx[p];
        int pos = offs[r] + atomicAdd(&cur[r], 1);
        sorted[pos] = p;   // bucket order nondeterministic; e values are not
    }
}

// ---------- fused v7: producer/consumer wave specialization ----------
// Waves 0-2 stream one 16-row segment each per interval (issue next interval's
// loads early; stage current regs -> LDS + shifted aligned out-stores; raw
// s_barrier). Wave 3 dots the PREVIOUS interval's 48 rows from the other LDS
// buffer (pair-per-lane, embeds L2-resident). Separate waves = separate vmcnt
// counters: the consumer's latency stalls never drain the producers' stream.
__global__ __launch_bounds__(256) void fused7_kernel(
    const float* __restrict__ mem1, const float* __restrict__ mem2,
    const float* __restrict__ teacher, const float* __restrict__ student,
    const int* __restrict__ offs, const int* __restrict__ sorted,
    const int* __restrict__ cidx,
    float* __restrict__ out, float* __restrict__ e2, float* __restrict__ e1)
{
    __shared__ float buf[2][3 * kSegRows * kLdsStride];   // 2 x 48 rows
    const int tid = threadIdx.x;
    const int lane = tid & 63;
    const int w = tid >> 6;

    const int segBase = blockIdx.x * kSPB;
    int segEnd = segBase + kSPB; if (segEnd > kSegs) segEnd = kSegs;

    if (blockIdx.x == 0 && tid == 0) out[kTot] = mem2[kM - 1];  // final tail

    const float4* m1v = reinterpret_cast<const float4*>(mem1);
    const float4* m2v = reinterpret_cast<const float4*>(mem2);
    float4* ov = reinterpret_cast<float4*>(out);

    if (w < 3) {
        // ================= producer =================
        float4 ra[8], rb[8];
        float ca = 0.f, cb = 0.f;

        auto issue = [&](float4 (&r)[8], float& carry, int s) {
            bool b1 = (s < kSegsB1);
            const float4* bp = b1 ? m1v : m2v;
            long long base4 = (long long)(b1 ? s : s - kSegsB1) * kSegF4;
            #pragma unroll
            for (int i = 0; i < 8; ++i) r[i] = bp[base4 + i * 64 + lane];
            carry = 0.f;
            long long cg = (long long)s * (kSegRows * kD) - 1;
            if (cg >= 0) carry = (cg < kM) ? mem1[cg] : mem2[cg - kM];
        };

        auto stage = [&](float4 (&r)[8], float carry, float* bufp, int s) {
            long long g4 = (long long)s * kSegF4;
            float* wrows = bufp + w * kSegRows * kLdsStride;
            #pragma unroll
            for (int i = 0; i < 8; ++i) {
                float4 c = r[i];
                int lr = i * 2 + (lane >> 5);
                *reinterpret_cast<float4*>(&wrows[lr * kLdsStride + (lane & 31) * 4]) = c;
                float pw = __shfl_up(c.w, 1);
                if (lane == 0) pw = carry;
                carry = __shfl(c.w, 63);
                long long k4 = g4 + i * 64 + lane;
                if (k4 != 0) {
                    ov[k4] = make_float4(pw, c.x, c.y, c.z);
                } else {
                    out[1] = c.x; out[2] = c.y; out[3] = c.z;
                }
            }
        };

        // prologue: interval 0 loads
        int sp = segBase + w;
        bool act0 = (sp < segEnd);
        if (act0) issue(ra, ca, sp);

        auto step = [&](int j, float4 (&cur)[8], float& ccur,
                        float4 (&nxt)[8], float& cnxt) {
            int sn = segBase + (j + 1) * 3 + w;
            if ((j + 1) < kNIprod && sn < segEnd) issue(nxt, cnxt, sn);
            __builtin_amdgcn_sched_barrier(0);
            int sc = segBase + j * 3 + w;
            if (j < kNIprod && sc < segEnd) stage(cur, ccur, buf[j & 1], sc);
            asm volatile("s_waitcnt lgkmcnt(0)" ::: "memory");
            __builtin_amdgcn_sched_barrier(0);
            __builtin_amdgcn_s_barrier();
            __builtin_amdgcn_sched_barrier(0);
        };

        for (int j = 0; j < kNI; j += 2) {
            step(j, ra, ca, rb, cb);
            if (j + 1 < kNI) step(j + 1, rb, cb, ra, ca);
        }
    } else {
        // ================= consumer =================
        for (int j = 0; j < kNI; ++j) {
            if (j >= 1) {
                const float* bufp = buf[(j - 1) & 1];
                #pragma unroll
                for (int q = 0; q < 3; ++q) {
                    int s = segBase + (j - 1) * 3 + q;
                    if (s >= segEnd) continue;
                    bool b1 = (s < kSegsB1);
                    int rowbase = (b1 ? s : s - kSegsB1) * kSegRows;
                    int o0  = offs[rowbase];
                    int cnt = offs[rowbase + kSegRows] - o0;
                    const float4* emb4 =
                        reinterpret_cast<const float4*>(b1 ? teacher : student);
                    float* ep = b1 ? e2 : e1;
                    const float* rows = bufp + q * kSegRows * kLdsStride;
                    for (int t = lane; t < cnt; t += 64) {
                        int p  = sorted[o0 + t];
                        int lr = cidx[p] - rowbase;
                        unsigned bb = (unsigned)p / (unsigned)kKC;
                        const float4* er = emb4 + (long long)bb * 32;
                        const float* row = &rows[lr * kLdsStride];
                        float ax = 0.f, ay = 0.f, az = 0.f, aw = 0.f;
                        #pragma unroll 8
                        for (int kk = 0; kk < 32; ++kk) {
                            float4 rv = *reinterpret_cast<const float4*>(&row[kk * 4]);
                            float4 ev = er[kk];
                            ax += rv.x * ev.x; ay += rv.y * ev.y;
                            az += rv.z * ev.z; aw += rv.w * ev.w;
                        }
                        ep[p] = __expf((ax + ay + az + aw) * kTInv);
                    }
                }
            }
            asm volatile("s_waitcnt lgkmcnt(0)" ::: "memory");
            __builtin_amdgcn_sched_barrier(0);
            __builtin_amdgcn_s_barrier();
            __builtin_amdgcn_sched_barrier(0);
        }
    }
}

// ---------- fallback path (R2): separate gather + copy ----------

__global__ __launch_bounds__(256) void dots_kernel(
    const float* __restrict__ mem1, const float* __restrict__ mem2,
    const float* __restrict__ teacher, const float* __restrict__ student,
    const int* __restrict__ cidx,
    float* __restrict__ e2, float* __restrict__ e1)
{
    int gtid = blockIdx.x * 256 + threadIdx.x;
    int wave = gtid >> 6;
    int lane = threadIdx.x & 63;
    if (wave >= kNPair) return;
    int b = wave / kKC;
    long long row = (long long)cidx[wave] * kD;
    const float2 m1 = *reinterpret_cast<const float2*>(mem1 + row + lane * 2);
    const float2 m2 = *reinterpret_cast<const float2*>(mem2 + row + lane * 2);
    const float2 tv = *reinterpret_cast<const float2*>(teacher + b * kD + lane * 2);
    const float2 sv = *reinterpret_cast<const float2*>(student + b * kD + lane * 2);
    float d1 = m1.x * tv.x + m1.y * tv.y;
    float d2 = m2.x * sv.x + m2.y * sv.y;
    #pragma unroll
    for (int off = 32; off > 0; off >>= 1) {
        d1 += __shfl_xor(d1, off);
        d2 += __shfl_xor(d2, off);
    }
    if (lane == 0) {
        e2[wave] = __expf(d1 * kTInv);
        e1[wave] = __expf(d2 * kTInv);
    }
}

__global__ __launch_bounds__(256) void copy_kernel(
    const float* __restrict__ mem1, const float* __restrict__ mem2,
    float* __restrict__ out)
{
    const long long NV4 = (kTot + 1) / 4;
    const long long KS  = kM / 4;
    const float4* m1v = reinterpret_cast<const float4*>(mem1);
    const float4* m2v = reinterpret_cast<const float4*>(mem2);
    float4* ov = reinterpret_cast<float4*>(out);
    long long stride = (long long)gridDim.x * 256;
    for (long long k = (long long)blockIdx.x * 256 + threadIdx.x; k < NV4; k += stride) {
        if (k == 0) {
            out[1] = mem1[0]; out[2] = mem1[1]; out[3] = mem1[2];
            out[kTot] = mem2[kM - 1];
            continue;
        }
        float4 r;
        if (k < KS) {
            float4 a = m1v[k - 1];
            float4 b = m1v[k];
            r = make_float4(a.w, b.x, b.y, b.z);
        } else if (k == KS) {
            r = make_float4(mem1[kM - 1], mem2[0], mem2[1], mem2[2]);
        } else {
            float4 a = m2v[k - KS - 1];
            float4 b = m2v[k - KS];
            r = make_float4(a.w, b.x, b.y, b.z);
        }
        ov[k] = r;
    }
}

// ---------- loss chain ----------

__global__ __launch_bounds__(256) void sums_kernel(
    const float* __restrict__ e2, const float* __restrict__ e1,
    float* __restrict__ p2, float* __restrict__ p1)
{
    __shared__ float s2[256], s1[256];
    float a2 = 0.f, a1 = 0.f;
    for (int i = blockIdx.x * 256 + threadIdx.x; i < kNPair; i += 256 * kRB) {
        a2 += e2[i];
        a1 += e1[i];
    }
    s2[threadIdx.x] = a2; s1[threadIdx.x] = a1;
    __syncthreads();
    for (int st = 128; st > 0; st >>= 1) {
        if ((int)threadIdx.x < st) {
            s2[threadIdx.x] += s2[threadIdx.x + st];
            s1[threadIdx.x] += s1[threadIdx.x + st];
        }
        __syncthreads();
    }
    if (threadIdx.x == 0) { p2[blockIdx.x] = s2[0]; p1[blockIdx.x] = s1[0]; }
}

__global__ __launch_bounds__(256) void z_kernel(
    const float* __restrict__ p2, const float* __restrict__ p1, float* __restrict__ z)
{
    __shared__ float s2[256], s1[256];
    s2[threadIdx.x] = p2[threadIdx.x];
    s1[threadIdx.x] = p1[threadIdx.x];
    __syncthreads();
    for (int st = 128; st > 0; st >>= 1) {
        if ((int)threadIdx.x < st) {
            s2[threadIdx.x] += s2[threadIdx.x + st];
            s1[threadIdx.x] += s1[threadIdx.x + st];
        }
        __syncthreads();
    }
    if (threadIdx.x == 0) {
        const float scale = (float)kN / (float)kNPair;
        z[0] = s2[0] * scale;   // z_v2
        z[1] = s1[0] * scale;   // z_v1
    }
}

__global__ __launch_bounds__(256) void lossp_kernel(
    const float* __restrict__ e2, const float* __restrict__ e1,
    const float* __restrict__ z, float* __restrict__ lp)
{
    const float mpn = 2048.0f / 500000.0f;
    const float noise = mpn + 1e-7f;
    const float iz2 = 1.0f / z[0];
    const float iz1 = 1.0f / z[1];
    float acc = 0.f;
    for (int i = blockIdx.x * 256 + threadIdx.x; i < kNPair; i += 256 * kRB) {
        int k = i % kKC;
        float x2 = e2[i] * iz2;
        float x1 = e1[i] * iz1;
        if (k == 0) {
            acc += __logf(x2 / (x2 + noise)) + __logf(x1 / (x1 + noise));
        } else {
            acc += __logf(mpn / (x2 + noise)) + __logf(mpn / (x1 + noise));
        }
    }
    __shared__ float s[256];
    s[threadIdx.x] = acc;
    __syncthreads();
    for (int st = 128; st > 0; st >>= 1) {
        if ((int)threadIdx.x < st) s[threadIdx.x] += s[threadIdx.x + st];
        __syncthreads();
    }
    if (threadIdx.x == 0) lp[blockIdx.x] = s[0];
}

__global__ __launch_bounds__(256) void final_kernel(
    const float* __restrict__ lp, float* __restrict__ out)
{
    __shared__ float s[256];
    s[threadIdx.x] = lp[threadIdx.x];
    __syncthreads();
    for (int st = 128; st > 0; st >>= 1) {
        if ((int)threadIdx.x < st) s[threadIdx.x] += s[threadIdx.x + st];
        __syncthreads();
    }
    if (threadIdx.x == 0) out[0] = -s[0] / (float)kB;
}

// ---------- momentum update of the 256 pos rows ----------

__global__ __launch_bounds__(64) void update_kernel(
    const float* __restrict__ mem1, const float* __restrict__ mem2,
    const float* __restrict__ student, const float* __restrict__ teacher,
    const int* __restrict__ pos_idx,
    float* __restrict__ out1, float* __restrict__ out2)
{
    int b = blockIdx.x;
    int lane = threadIdx.x;
    int p = pos_idx[b];
    for (int b2 = b + 1; b2 < kB; ++b2)
        if (pos_idx[b2] == p) return;   // a later write wins
    long long row = (long long)p * kD;
    float2 m1 = *reinterpret_cast<const float2*>(mem1 + row + lane * 2);
    float2 m2 = *reinterpret_cast<const float2*>(mem2 + row + lane * 2);
    float2 sv = *reinterpret_cast<const float2*>(student + b * kD + lane * 2);
    float2 tv = *reinterpret_cast<const float2*>(teacher + b * kD + lane * 2);
    float2 l1 = make_float2(m1.x * kMom + sv.x * (1.f - kMom),
                            m1.y * kMom + sv.y * (1.f - kMom));
    float2 l2 = make_float2(m2.x * kMom + tv.x * (1.f - kMom),
                            m2.y * kMom + tv.y * (1.f - kMom));
    float n1 = l1.x * l1.x + l1.y * l1.y;
    float n2 = l2.x * l2.x + l2.y * l2.y;
    #pragma unroll
    for (int off = 32; off > 0; off >>= 1) {
        n1 += __shfl_xor(n1, off);
        n2 += __shfl_xor(n2, off);
    }
    float i1 = 1.0f / sqrtf(n1);
    float i2 = 1.0f / sqrtf(n2);
    out1[row + lane * 2]     = l1.x * i1;
    out1[row + lane * 2 + 1] = l1.y * i1;
    out2[row + lane * 2]     = l2.x * i2;
    out2[row + lane * 2 + 1] = l2.y * i2;
}

extern "C" void kernel_launch(void* const* d_in, const int* in_sizes, int n_in,
                              void* d_out, int out_size, void* d_ws, size_t ws_size,
                              hipStream_t stream) {
    const float* student = (const float*)d_in[0];
    const float* teacher = (const float*)d_in[1];
    const float* mem1    = (const float*)d_in[2];
    const float* mem2    = (const float*)d_in[3];
    const int*   pos_idx = (const int*)d_in[4];
    const int*   cidx    = (const int*)d_in[5];

    float* out  = (float*)d_out;
    float* out1 = out + 1;
    float* out2 = out + 1 + kM;

    // ws layout
    float* ws = (float*)d_ws;
    float* e2 = ws;                         // kNPair
    float* e1 = e2 + kNPair;                // kNPair
    float* p2 = e1 + kNPair;                // kRB
    float* p1 = p2 + kRB;                   // kRB
    float* zz = p1 + kRB;                   // 2
    float* lp = zz + 2;                     // kRB
    int*   A      = (int*)(lp + kRB);       // kN   (counts)
    int*   cur    = A + kN;                 // kN   (scatter cursor)
    int*   offs   = cur + kN;               // kN + 1
    int*   bsum   = offs + kN + 1;          // kNB1
    int*   bpre   = bsum + kNB1;            // kNB1
    int*   sorted = bpre + kNB1;            // kNPair
    size_t need = (size_t)((char*)(sorted + kNPair) - (char*)d_ws);

    if (ws_size >= need) {
        // CSR setup
        zero2_kernel<<<(kN + 255) / 256, 256, 0, stream>>>(A, cur);
        hist_kernel<<<(kNPair + 255) / 256, 256, 0, stream>>>(cidx, A);
        scan1_kernel<<<kNB1, 256, 0, stream>>>(A, bsum);
        scan2_kernel<<<1, 256, 0, stream>>>(bsum, bpre, offs);
        scan3_kernel<<<kNB1, 256, 0, stream>>>(A, bpre, offs);
        scatter_kernel<<<(kNPair + 255) / 256, 256, 0, stream>>>(cidx, offs, cur, sorted);
        // producer/consumer fused streaming copy + dots
        fused7_kernel<<<kGrid7, 256, 0, stream>>>(mem1, mem2, teacher, student,
                                                  offs, sorted, cidx, out, e2, e1);
    } else {
        // fallback: R2 path
        int nblocks = (kNPair + 3) / 4;
        dots_kernel<<<nblocks, 256, 0, stream>>>(mem1, mem2, teacher, student, cidx, e2, e1);
        copy_kernel<<<2048, 256, 0, stream>>>(mem1, mem2, out);
    }

    sums_kernel<<<kRB, 256, 0, stream>>>(e2, e1, p2, p1);
    z_kernel<<<1, 256, 0, stream>>>(p2, p1, zz);
    lossp_kernel<<<kRB, 256, 0, stream>>>(e2, e1, zz, lp);
    final_kernel<<<1, 256, 0, stream>>>(lp, out);
    update_kernel<<<kB, 64, 0, stream>>>(mem1, mem2, student, teacher, pos_idx, out1, out2);
}

// Round 10
// 358.986 us; speedup vs baseline: 1.3253x; 1.3253x over previous
//
#include <hip/hip_runtime.h>
#include <math.h>

namespace {
constexpr int kB = 256;
constexpr int kD = 128;
constexpr int kN = 500000;
constexpr int kKC = 2049;             // K + 1
constexpr int kNPair = kB * kKC;      // 524544
constexpr float kTInv = 1.0f / 0.07f;
constexpr float kMom = 0.5f;
constexpr int kRB = 256;              // reduction grid size
constexpr long long kM = (long long)kN * kD;    // 64,000,000 floats per bank
constexpr long long kTot = 2 * kM;
constexpr int kChunk = 2048;                    // elems per scan block
constexpr int kNB1 = (kN + kChunk - 1) / kChunk; // 245
// fused8 geometry: 32-row tiles (exact: 500000/32 = 15625), 16 tiles/block
constexpr int kRows = 32;
constexpr int kTPB = kN / kRows;                 // 15625 tiles per bank (exact)
constexpr int kTiles = 2 * kTPB;                 // 31250
constexpr int kLdsStride = 132;                  // 528 B row pitch (16B-aligned)
constexpr int kTilesPerBlock = 16;
constexpr int kGrid8 = (kTiles + kTilesPerBlock - 1) / kTilesPerBlock; // 1954
}

// ---------- CSR setup: bucket pairs by row index ----------

__global__ __launch_bounds__(256) void hist_kernel(const int* __restrict__ cidx, int* __restrict__ A)
{
    int i = blockIdx.x * 256 + threadIdx.x;
    if (i < kNPair) atomicAdd(&A[cidx[i]], 1);
}

__global__ __launch_bounds__(256) void scan1_kernel(const int* __restrict__ A, int* __restrict__ bsum)
{
    long long base = (long long)blockIdx.x * kChunk;
    int t = threadIdx.x;
    int s = 0;
    #pragma unroll
    for (int j = 0; j < 8; ++j) {
        long long i = base + t * 8 + j;
        if (i < kN) s += A[i];
    }
    __shared__ int lds[256];
    lds[t] = s; __syncthreads();
    for (int st = 128; st > 0; st >>= 1) {
        if (t < st) lds[t] += lds[t + st];
        __syncthreads();
    }
    if (t == 0) bsum[blockIdx.x] = lds[0];
}

__global__ __launch_bounds__(256) void scan2_kernel(
    const int* __restrict__ bsum, int* __restrict__ bpre, int* __restrict__ offs)
{
    int t = threadIdx.x;
    int v = (t < kNB1) ? bsum[t] : 0;
    __shared__ int lds[256];
    lds[t] = v; __syncthreads();
    for (int st = 1; st < 256; st <<= 1) {
        int add = (t >= st) ? lds[t - st] : 0;
        __syncthreads();
        lds[t] += add;
        __syncthreads();
    }
    if (t < kNB1) bpre[t] = lds[t] - v;       // exclusive
    if (t == kNB1 - 1) offs[kN] = lds[t];     // total = kNPair
}

__global__ __launch_bounds__(256) void scan3_kernel(
    const int* __restrict__ A, const int* __restrict__ bpre, int* __restrict__ offs)
{
    int t = threadIdx.x;
    long long base = (long long)blockIdx.x * kChunk;
    int c[8]; int s = 0;
    #pragma unroll
    for (int j = 0; j < 8; ++j) {
        long long i = base + t * 8 + j;
        c[j] = (i < kN) ? A[i] : 0;
        s += c[j];
    }
    __shared__ int lds[256];
    lds[t] = s; __syncthreads();
    for (int st = 1; st < 256; st <<= 1) {
        int add = (t >= st) ? lds[t - st] : 0;
        __syncthreads();
        lds[t] += add;
        __syncthreads();
    }
    int excl = lds[t] - s + bpre[blockIdx.x];
    #pragma unroll
    for (int j = 0; j < 8; ++j) {
        long long i = base + t * 8 + j;
        if (i < kN) { offs[i] = excl; excl += c[j]; }
    }
}

// packs (row << 20) | pair so phase B needs ONE load per pair (no cidx chase)
__global__ __launch_bounds__(256) void scatter_kernel(
    const int* __restrict__ cidx, const int* __restrict__ offs,
    int* __restrict__ cur, long long* __restrict__ sorted64)
{
    int p = blockIdx.x * 256 + threadIdx.x;
    if (p < kNPair) {
        int r = cidx[p];
        int pos = offs[r] + atomicAdd(&cur[r], 1);
        sorted64[pos] = ((long long)r << 20) | (long long)p;
    }
}

// ---------- fused v8: 32-row tiles, 8+ blocks/CU for phase decorrelation ----------
// Per tile: Phase A streams the 16KB tile (4 float4/thread), stages rows in
// LDS (132-float pitch) and emits the shifted aligned float4 output stores
// (carry trick). Phase B: one pair per LANE reads its row from LDS and dots
// against the L2-resident embed (packed sorted64: no cidx load). With 16.9KB
// LDS, 8-9 blocks/CU are co-resident: while one block sits in its
// latency-bound phase B, the others keep HBM saturated.
__global__ __launch_bounds__(256) void fused8_kernel(
    const float* __restrict__ mem1, const float* __restrict__ mem2,
    const float* __restrict__ teacher, const float* __restrict__ student,
    const int* __restrict__ offs, const long long* __restrict__ sorted64,
    float* __restrict__ out, float* __restrict__ e2, float* __restrict__ e1)
{
    __shared__ float tile[kRows * kLdsStride];
    const int tid = threadIdx.x;
    const int lane = tid & 63;
    const int w = tid >> 6;
    float4* ov = reinterpret_cast<float4*>(out);

    if (blockIdx.x == 0 && tid == 0) out[kTot] = mem2[kM - 1];  // final tail

    const int T0 = blockIdx.x * kTilesPerBlock;
    int T1 = T0 + kTilesPerBlock; if (T1 > kTiles) T1 = kTiles;

    for (int T = T0; T < T1; ++T) {
        const int bk = (T >= kTPB) ? 1 : 0;
        const int tt = T - bk * kTPB;
        const int r0 = tt * kRows;

        // ---- Phase A: stream tile, stage LDS, shifted out-stores ----
        {
            const float4* bank4 = reinterpret_cast<const float4*>(bk ? mem2 : mem1);
            const long long lb4 = (long long)tt * (kRows * kD / 4) + w * 256;
            float4 v[4];
            #pragma unroll
            for (int i = 0; i < 4; ++i) v[i] = bank4[lb4 + i * 64 + lane];

            const long long gbase = (long long)bk * kM + (long long)r0 * kD
                                    + (long long)w * 1024;       // concat float idx
            float carry = 0.f;
            if (gbase > 0) {
                long long g = gbase - 1;
                carry = (g < kM) ? mem1[g] : mem2[g - kM];
            }
            const long long g4 = gbase >> 2;
            #pragma unroll
            for (int i = 0; i < 4; ++i) {
                float4 c = v[i];
                int lr = w * 8 + i * 2 + (lane >> 5);
                *reinterpret_cast<float4*>(&tile[lr * kLdsStride + (lane & 31) * 4]) = c;
                float pw = __shfl_up(c.w, 1);
                if (lane == 0) pw = carry;
                carry = __shfl(c.w, 63);
                long long k4 = g4 + i * 64 + lane;
                if (k4 != 0) {
                    ov[k4] = make_float4(pw, c.x, c.y, c.z);
                } else {
                    out[1] = c.x; out[2] = c.y; out[3] = c.z;
                }
            }
        }
        __syncthreads();

        // ---- Phase B: pair-per-lane dots from LDS ----
        {
            const int o0  = offs[r0];
            const int cnt = offs[r0 + kRows] - o0;
            const float4* emb4 =
                reinterpret_cast<const float4*>(bk ? student : teacher);
            float* ep = bk ? e1 : e2;   // bank1 -> e2 (teacher), bank2 -> e1
            for (int t = tid; t < cnt; t += 256) {
                long long v = sorted64[o0 + t];
                int p  = (int)(v & 0xFFFFF);
                int lr = (int)(v >> 20) - r0;
                unsigned bb = (unsigned)p / (unsigned)kKC;
                const float4* er = emb4 + (long long)bb * 32;
                const float* row = &tile[lr * kLdsStride];
                float ax = 0.f, ay = 0.f, az = 0.f, aw = 0.f;
                #pragma unroll 8
                for (int kk = 0; kk < 32; ++kk) {
                    float4 rv = *reinterpret_cast<const float4*>(&row[kk * 4]);
                    float4 ev = er[kk];
                    ax += rv.x * ev.x; ay += rv.y * ev.y;
                    az += rv.z * ev.z; aw += rv.w * ev.w;
                }
                ep[p] = __expf((ax + ay + az + aw) * kTInv);
            }
        }
        __syncthreads();
    }
}

// ---------- fallback path (R2): separate gather + copy ----------

__global__ __launch_bounds__(256) void dots_kernel(
    const float* __restrict__ mem1, const float* __restrict__ mem2,
    const float* __restrict__ teacher, const float* __restrict__ student,
    const int* __restrict__ cidx,
    float* __restrict__ e2, float* __restrict__ e1)
{
    int gtid = blockIdx.x * 256 + threadIdx.x;
    int wave = gtid >> 6;
    int lane = threadIdx.x & 63;
    if (wave >= kNPair) return;
    int b = wave / kKC;
    long long row = (long long)cidx[wave] * kD;
    const float2 m1 = *reinterpret_cast<const float2*>(mem1 + row + lane * 2);
    const float2 m2 = *reinterpret_cast<const float2*>(mem2 + row + lane * 2);
    const float2 tv = *reinterpret_cast<const float2*>(teacher + b * kD + lane * 2);
    const float2 sv = *reinterpret_cast<const float2*>(student + b * kD + lane * 2);
    float d1 = m1.x * tv.x + m1.y * tv.y;
    float d2 = m2.x * sv.x + m2.y * sv.y;
    #pragma unroll
    for (int off = 32; off > 0; off >>= 1) {
        d1 += __shfl_xor(d1, off);
        d2 += __shfl_xor(d2, off);
    }
    if (lane == 0) {
        e2[wave] = __expf(d1 * kTInv);
        e1[wave] = __expf(d2 * kTInv);
    }
}

__global__ __launch_bounds__(256) void copy_kernel(
    const float* __restrict__ mem1, const float* __restrict__ mem2,
    float* __restrict__ out)
{
    const long long NV4 = (kTot + 1) / 4;
    const long long KS  = kM / 4;
    const float4* m1v = reinterpret_cast<const float4*>(mem1);
    const float4* m2v = reinterpret_cast<const float4*>(mem2);
    float4* ov = reinterpret_cast<float4*>(out);
    long long stride = (long long)gridDim.x * 256;
    for (long long k = (long long)blockIdx.x * 256 + threadIdx.x; k < NV4; k += stride) {
        if (k == 0) {
            out[1] = mem1[0]; out[2] = mem1[1]; out[3] = mem1[2];
            out[kTot] = mem2[kM - 1];
            continue;
        }
        float4 r;
        if (k < KS) {
            float4 a = m1v[k - 1];
            float4 b = m1v[k];
            r = make_float4(a.w, b.x, b.y, b.z);
        } else if (k == KS) {
            r = make_float4(mem1[kM - 1], mem2[0], mem2[1], mem2[2]);
        } else {
            float4 a = m2v[k - KS - 1];
            float4 b = m2v[k - KS];
            r = make_float4(a.w, b.x, b.y, b.z);
        }
        ov[k] = r;
    }
}

// ---------- loss chain ----------

__global__ __launch_bounds__(256) void sums_kernel(
    const float* __restrict__ e2, const float* __restrict__ e1,
    float* __restrict__ p2, float* __restrict__ p1)
{
    __shared__ float s2[256], s1[256];
    float a2 = 0.f, a1 = 0.f;
    for (int i = blockIdx.x * 256 + threadIdx.x; i < kNPair; i += 256 * kRB) {
        a2 += e2[i];
        a1 += e1[i];
    }
    s2[threadIdx.x] = a2; s1[threadIdx.x] = a1;
    __syncthreads();
    for (int st = 128; st > 0; st >>= 1) {
        if ((int)threadIdx.x < st) {
            s2[threadIdx.x] += s2[threadIdx.x + st];
            s1[threadIdx.x] += s1[threadIdx.x + st];
        }
        __syncthreads();
    }
    if (threadIdx.x == 0) { p2[blockIdx.x] = s2[0]; p1[blockIdx.x] = s1[0]; }
}

__global__ __launch_bounds__(256) void z_kernel(
    const float* __restrict__ p2, const float* __restrict__ p1, float* __restrict__ z)
{
    __shared__ float s2[256], s1[256];
    s2[threadIdx.x] = p2[threadIdx.x];
    s1[threadIdx.x] = p1[threadIdx.x];
    __syncthreads();
    for (int st = 128; st > 0; st >>= 1) {
        if ((int)threadIdx.x < st) {
            s2[threadIdx.x] += s2[threadIdx.x + st];
            s1[threadIdx.x] += s1[threadIdx.x + st];
        }
        __syncthreads();
    }
    if (threadIdx.x == 0) {
        const float scale = (float)kN / (float)kNPair;
        z[0] = s2[0] * scale;   // z_v2
        z[1] = s1[0] * scale;   // z_v1
    }
}

__global__ __launch_bounds__(256) void lossp_kernel(
    const float* __restrict__ e2, const float* __restrict__ e1,
    const float* __restrict__ z, float* __restrict__ lp)
{
    const float mpn = 2048.0f / 500000.0f;
    const float noise = mpn + 1e-7f;
    const float iz2 = 1.0f / z[0];
    const float iz1 = 1.0f / z[1];
    float acc = 0.f;
    for (int i = blockIdx.x * 256 + threadIdx.x; i < kNPair; i += 256 * kRB) {
        int k = i % kKC;
        float x2 = e2[i] * iz2;
        float x1 = e1[i] * iz1;
        if (k == 0) {
            acc += __logf(x2 / (x2 + noise)) + __logf(x1 / (x1 + noise));
        } else {
            acc += __logf(mpn / (x2 + noise)) + __logf(mpn / (x1 + noise));
        }
    }
    __shared__ float s[256];
    s[threadIdx.x] = acc;
    __syncthreads();
    for (int st = 128; st > 0; st >>= 1) {
        if ((int)threadIdx.x < st) s[threadIdx.x] += s[threadIdx.x + st];
        __syncthreads();
    }
    if (threadIdx.x == 0) lp[blockIdx.x] = s[0];
}

__global__ __launch_bounds__(256) void final_kernel(
    const float* __restrict__ lp, float* __restrict__ out)
{
    __shared__ float s[256];
    s[threadIdx.x] = lp[threadIdx.x];
    __syncthreads();
    for (int st = 128; st > 0; st >>= 1) {
        if ((int)threadIdx.x < st) s[threadIdx.x] += s[threadIdx.x + st];
        __syncthreads();
    }
    if (threadIdx.x == 0) out[0] = -s[0] / (float)kB;
}

// ---------- momentum update of the 256 pos rows ----------

__global__ __launch_bounds__(64) void update_kernel(
    const float* __restrict__ mem1, const float* __restrict__ mem2,
    const float* __restrict__ student, const float* __restrict__ teacher,
    const int* __restrict__ pos_idx,
    float* __restrict__ out1, float* __restrict__ out2)
{
    int b = blockIdx.x;
    int lane = threadIdx.x;
    int p = pos_idx[b];
    for (int b2 = b + 1; b2 < kB; ++b2)
        if (pos_idx[b2] == p) return;   // a later write wins
    long long row = (long long)p * kD;
    float2 m1 = *reinterpret_cast<const float2*>(mem1 + row + lane * 2);
    float2 m2 = *reinterpret_cast<const float2*>(mem2 + row + lane * 2);
    float2 sv = *reinterpret_cast<const float2*>(student + b * kD + lane * 2);
    float2 tv = *reinterpret_cast<const float2*>(teacher + b * kD + lane * 2);
    float2 l1 = make_float2(m1.x * kMom + sv.x * (1.f - kMom),
                            m1.y * kMom + sv.y * (1.f - kMom));
    float2 l2 = make_float2(m2.x * kMom + tv.x * (1.f - kMom),
                            m2.y * kMom + tv.y * (1.f - kMom));
    float n1 = l1.x * l1.x + l1.y * l1.y;
    float n2 = l2.x * l2.x + l2.y * l2.y;
    #pragma unroll
    for (int off = 32; off > 0; off >>= 1) {
        n1 += __shfl_xor(n1, off);
        n2 += __shfl_xor(n2, off);
    }
    float i1 = 1.0f / sqrtf(n1);
    float i2 = 1.0f / sqrtf(n2);
    out1[row + lane * 2]     = l1.x * i1;
    out1[row + lane * 2 + 1] = l1.y * i1;
    out2[row + lane * 2]     = l2.x * i2;
    out2[row + lane * 2 + 1] = l2.y * i2;
}

extern "C" void kernel_launch(void* const* d_in, const int* in_sizes, int n_in,
                              void* d_out, int out_size, void* d_ws, size_t ws_size,
                              hipStream_t stream) {
    const float* student = (const float*)d_in[0];
    const float* teacher = (const float*)d_in[1];
    const float* mem1    = (const float*)d_in[2];
    const float* mem2    = (const float*)d_in[3];
    const int*   pos_idx = (const int*)d_in[4];
    const int*   cidx    = (const int*)d_in[5];

    float* out  = (float*)d_out;
    float* out1 = out + 1;
    float* out2 = out + 1 + kM;

    // ws layout (sorted64 placed right after e-arrays: byte offset divisible by 8)
    float* ws = (float*)d_ws;
    float* e2 = ws;                            // kNPair
    float* e1 = e2 + kNPair;                   // kNPair
    long long* sorted64 = (long long*)(e1 + kNPair);   // kNPair (8B each)
    float* p2 = (float*)(sorted64 + kNPair);   // kRB
    float* p1 = p2 + kRB;                      // kRB
    float* zz = p1 + kRB;                      // 2
    float* lp = zz + 2;                        // kRB
    int*   A    = (int*)(lp + kRB);            // kN counts
    int*   cur  = A + kN;                      // kN scatter cursor
    int*   offs = cur + kN;                    // kN + 1
    int*   bsum = offs + kN + 1;               // kNB1
    int*   bpre = bsum + kNB1;                 // kNB1
    size_t need = (size_t)((char*)(bpre + kNB1) - (char*)d_ws);

    if (ws_size >= need) {
        // CSR setup (A and cur zeroed in one async memset)
        hipMemsetAsync(A, 0, 2 * (size_t)kN * sizeof(int), stream);
        hist_kernel<<<(kNPair + 255) / 256, 256, 0, stream>>>(cidx, A);
        scan1_kernel<<<kNB1, 256, 0, stream>>>(A, bsum);
        scan2_kernel<<<1, 256, 0, stream>>>(bsum, bpre, offs);
        scan3_kernel<<<kNB1, 256, 0, stream>>>(A, bpre, offs);
        scatter_kernel<<<(kNPair + 255) / 256, 256, 0, stream>>>(cidx, offs, cur, sorted64);
        // fused tiled copy + dots, 8+ blocks/CU
        fused8_kernel<<<kGrid8, 256, 0, stream>>>(mem1, mem2, teacher, student,
                                                  offs, sorted64, out, e2, e1);
    } else {
        // fallback: R2 path
        int nblocks = (kNPair + 3) / 4;
        dots_kernel<<<nblocks, 256, 0, stream>>>(mem1, mem2, teacher, student, cidx, e2, e1);
        copy_kernel<<<2048, 256, 0, stream>>>(mem1, mem2, out);
    }

    sums_kernel<<<kRB, 256, 0, stream>>>(e2, e1, p2, p1);
    z_kernel<<<1, 256, 0, stream>>>(p2, p1, zz);
    lossp_kernel<<<kRB, 256, 0, stream>>>(e2, e1, zz, lp);
    final_kernel<<<1, 256, 0, stream>>>(lp, out);
    update_kernel<<<kB, 64, 0, stream>>>(mem1, mem2, student, teacher, pos_idx, out1, out2);
}

// Round 11
// 323.239 us; speedup vs baseline: 1.4719x; 1.1106x over previous
//
#include <hip/hip_runtime.h>
#include <math.h>

namespace {
constexpr int kB = 256;
constexpr int kD = 128;
constexpr int kN = 500000;
constexpr int kKC = 2049;             // K + 1
constexpr int kNPair = kB * kKC;      // 524544
constexpr float kTInv = 1.0f / 0.07f;
constexpr float kMom = 0.5f;
constexpr int kRB = 256;              // reduction grid size
constexpr long long kM = (long long)kN * kD;    // 64,000,000 floats per bank
constexpr long long kTot = 2 * kM;
constexpr int kChunk = 2048;                    // elems per scan block
constexpr int kNB1 = (kN + kChunk - 1) / kChunk; // 245
// fused9 geometry: 32-row tiles (exact: 500000/32 = 15625), 16 tiles/block
constexpr int kRows = 32;
constexpr int kTPB = kN / kRows;                 // 15625 tiles per bank (exact)
constexpr int kTiles = 2 * kTPB;                 // 31250
constexpr int kLdsStride = 132;                  // 528 B row pitch (16B-aligned)
constexpr int kTilesPerBlock = 16;
constexpr int kGrid9 = (kTiles + kTilesPerBlock - 1) / kTilesPerBlock; // 1954
}

// ---------- CSR setup: bucket pairs by row index ----------

__global__ __launch_bounds__(256) void hist_kernel(const int* __restrict__ cidx, int* __restrict__ A)
{
    int i = blockIdx.x * 256 + threadIdx.x;
    if (i < kNPair) atomicAdd(&A[cidx[i]], 1);
}

__global__ __launch_bounds__(256) void scan1_kernel(const int* __restrict__ A, int* __restrict__ bsum)
{
    long long base = (long long)blockIdx.x * kChunk;
    int t = threadIdx.x;
    int s = 0;
    #pragma unroll
    for (int j = 0; j < 8; ++j) {
        long long i = base + t * 8 + j;
        if (i < kN) s += A[i];
    }
    __shared__ int lds[256];
    lds[t] = s; __syncthreads();
    for (int st = 128; st > 0; st >>= 1) {
        if (t < st) lds[t] += lds[t + st];
        __syncthreads();
    }
    if (t == 0) bsum[blockIdx.x] = lds[0];
}

__global__ __launch_bounds__(256) void scan2_kernel(
    const int* __restrict__ bsum, int* __restrict__ bpre, int* __restrict__ offs)
{
    int t = threadIdx.x;
    int v = (t < kNB1) ? bsum[t] : 0;
    __shared__ int lds[256];
    lds[t] = v; __syncthreads();
    for (int st = 1; st < 256; st <<= 1) {
        int add = (t >= st) ? lds[t - st] : 0;
        __syncthreads();
        lds[t] += add;
        __syncthreads();
    }
    if (t < kNB1) bpre[t] = lds[t] - v;       // exclusive
    if (t == kNB1 - 1) offs[kN] = lds[t];     // total = kNPair
}

__global__ __launch_bounds__(256) void scan3_kernel(
    const int* __restrict__ A, const int* __restrict__ bpre, int* __restrict__ offs)
{
    int t = threadIdx.x;
    long long base = (long long)blockIdx.x * kChunk;
    int c[8]; int s = 0;
    #pragma unroll
    for (int j = 0; j < 8; ++j) {
        long long i = base + t * 8 + j;
        c[j] = (i < kN) ? A[i] : 0;
        s += c[j];
    }
    __shared__ int lds[256];
    lds[t] = s; __syncthreads();
    for (int st = 1; st < 256; st <<= 1) {
        int add = (t >= st) ? lds[t - st] : 0;
        __syncthreads();
        lds[t] += add;
        __syncthreads();
    }
    int excl = lds[t] - s + bpre[blockIdx.x];
    #pragma unroll
    for (int j = 0; j < 8; ++j) {
        long long i = base + t * 8 + j;
        if (i < kN) { offs[i] = excl; excl += c[j]; }
    }
}

// packs (row << 20) | pair so phase B needs ONE value per pair (no cidx chase)
__global__ __launch_bounds__(256) void scatter_kernel(
    const int* __restrict__ cidx, const int* __restrict__ offs,
    int* __restrict__ cur, long long* __restrict__ sorted64)
{
    int p = blockIdx.x * 256 + threadIdx.x;
    if (p < kNPair) {
        int r = cidx[p];
        int pos = offs[r] + atomicAdd(&cur[r], 1);
        sorted64[pos] = ((long long)r << 20) | (long long)p;
    }
}

// ---------- fused v9: full prefetch pipeline, short phase B ----------
// Per tile T: (1) issue T+1's stage loads + carry + sorted64 slice + T+2's
// offs (all stay in flight / land next iter); (2) stage(T): regs -> LDS +
// shifted aligned float4 out-stores (carry prefetched, no serial load);
// (3) raw s_barrier with lgkmcnt-only wait (T+1 stage loads NOT drained);
// (4) B(T): pair list read from LDS (prefetched), emb row loaded by a
// 4-lane group in ONE parallel L2 round-trip, 2-shuffle reduce, exp store.
// Phase B has no serial global chain -> high HBM duty cycle.
__global__ __launch_bounds__(256) void fused9_kernel(
    const float* __restrict__ mem1, const float* __restrict__ mem2,
    const float* __restrict__ teacher, const float* __restrict__ student,
    const int* __restrict__ offs, const long long* __restrict__ sorted64,
    float* __restrict__ out, float* __restrict__ e2, float* __restrict__ e1)
{
    __shared__ float tile[kRows * kLdsStride];   // 16896 B
    __shared__ long long s64lds[2][256];         // 4096 B
    const int tid = threadIdx.x;
    const int lane = tid & 63;
    const int w = tid >> 6;
    float4* ov = reinterpret_cast<float4*>(out);

    if (blockIdx.x == 0 && tid == 0) out[kTot] = mem2[kM - 1];  // final tail

    const int T0 = blockIdx.x * kTilesPerBlock;
    int T1 = T0 + kTilesPerBlock; if (T1 > kTiles) T1 = kTiles;
    const int nT = T1 - T0;

    auto r0of = [](int T) { return (T >= kTPB) ? (T - kTPB) * kRows : T * kRows; };

    // ---- prologue: offs(T0), offs(T0+1), s64(T0), SL(T0), carry(T0) ----
    int rA = r0of(T0);
    int oA = offs[rA];
    int cA = offs[rA + kRows] - oA;
    int TB = (1 < nT) ? T0 + 1 : T0;
    int rB = r0of(TB);
    int oB = offs[rB];
    int cB = (1 < nT) ? (offs[rB + kRows] - oB) : 0;
    {
        long long v = 0;
        if (tid < cA) v = sorted64[oA + tid];
        s64lds[0][tid] = v;
    }
    float4 sl0, sl1, sl2, sl3;
    float carry;
    {
        int bk = (T0 >= kTPB);
        const float4* bank4 = reinterpret_cast<const float4*>(bk ? mem2 : mem1);
        long long lb4 = (long long)(bk ? T0 - kTPB : T0) * (kRows * kD / 4) + w * 256;
        sl0 = bank4[lb4 + 0 * 64 + lane];
        sl1 = bank4[lb4 + 1 * 64 + lane];
        sl2 = bank4[lb4 + 2 * 64 + lane];
        sl3 = bank4[lb4 + 3 * 64 + lane];
        long long gb = (long long)bk * kM + (long long)rA * kD + (long long)w * 1024;
        carry = 0.f;
        if (gb > 0) { long long g = gb - 1; carry = (g < kM) ? mem1[g] : mem2[g - kM]; }
    }

    for (int i = 0; i < nT; ++i) {
        const int T = T0 + i;
        const int cur = i & 1;
        const int bk = (T >= kTPB) ? 1 : 0;
        const int r0 = r0of(T);
        const int o0 = oA, cnt = cA;

        // ---- prefetch SL + carry for T+1 (stay in flight across barriers) ----
        float4 sn0, sn1, sn2, sn3;
        float carryn;
        {
            int Tn = (i + 1 < nT) ? T + 1 : T;
            int bkn = (Tn >= kTPB);
            const float4* bank4 = reinterpret_cast<const float4*>(bkn ? mem2 : mem1);
            long long lb4 = (long long)(bkn ? Tn - kTPB : Tn) * (kRows * kD / 4) + w * 256;
            sn0 = bank4[lb4 + 0 * 64 + lane];
            sn1 = bank4[lb4 + 1 * 64 + lane];
            sn2 = bank4[lb4 + 2 * 64 + lane];
            sn3 = bank4[lb4 + 3 * 64 + lane];
            long long gb = (long long)bkn * kM + (long long)r0of(Tn) * kD + (long long)w * 1024;
            carryn = 0.f;
            if (gb > 0) { long long g = gb - 1; carryn = (g < kM) ? mem1[g] : mem2[g - kM]; }
        }
        // ---- prefetch sorted64 slice for T+1 ----
        long long s64n = 0;
        if (tid < cB) s64n = sorted64[oB + tid];
        // ---- prefetch offs for T+2 ----
        int oC, cC;
        {
            int Tn2 = (i + 2 < nT) ? T + 2 : T;
            int rn2 = r0of(Tn2);
            oC = offs[rn2];
            cC = (i + 2 < nT) ? (offs[rn2 + kRows] - oC) : 0;
        }
        __builtin_amdgcn_sched_barrier(0);

        // ---- stage(T): consume prefetched regs; LDS + shifted out stores ----
        {
            const long long gbase = (long long)bk * kM + (long long)r0 * kD
                                    + (long long)w * 1024;
            const long long g4 = gbase >> 2;
            float cr = carry;
            float4 v[4] = {sl0, sl1, sl2, sl3};
            #pragma unroll
            for (int i2 = 0; i2 < 4; ++i2) {
                float4 c = v[i2];
                int lr = w * 8 + i2 * 2 + (lane >> 5);
                *reinterpret_cast<float4*>(&tile[lr * kLdsStride + (lane & 31) * 4]) = c;
                float pw = __shfl_up(c.w, 1);
                if (lane == 0) pw = cr;
                cr = __shfl(c.w, 63);
                long long k4 = g4 + i2 * 64 + lane;
                if (k4 != 0) {
                    ov[k4] = make_float4(pw, c.x, c.y, c.z);
                } else {
                    out[1] = c.x; out[2] = c.y; out[3] = c.z;
                }
            }
        }
        asm volatile("s_waitcnt lgkmcnt(0)" ::: "memory");
        __builtin_amdgcn_sched_barrier(0);
        __builtin_amdgcn_s_barrier();
        __builtin_amdgcn_sched_barrier(0);

        // ---- B(T): pair dots; 4-lane cooperative emb load (one L2 trip) ----
        {
            // park next tile's pair list in the other LDS buffer
            s64lds[cur ^ 1][tid] = s64n;

            const float4* emb4 = reinterpret_cast<const float4*>(bk ? student : teacher);
            float* ep = bk ? e1 : e2;   // bank1 -> e2 (teacher), bank2 -> e1
            const int sub = tid & 3;
            for (int t = tid >> 2; t < cnt; t += 64) {
                long long v = (t < 256) ? s64lds[cur][t] : sorted64[o0 + t];
                int p  = (int)(v & 0xFFFFF);
                int lr = (int)(v >> 20) - r0;
                const float4* er = emb4
                    + (long long)((unsigned)p / (unsigned)kKC) * 32 + sub * 8;
                const float* row = &tile[lr * kLdsStride + sub * 32];
                float ax = 0.f, ay = 0.f, az = 0.f, aw = 0.f;
                #pragma unroll
                for (int kk = 0; kk < 8; ++kk) {
                    int c4 = (kk + sub * 2) & 7;     // bank-rotated chunk order
                    float4 ev = er[c4];
                    float4 rv = *reinterpret_cast<const float4*>(&row[c4 * 4]);
                    ax += rv.x * ev.x; ay += rv.y * ev.y;
                    az += rv.z * ev.z; aw += rv.w * ev.w;
                }
                float d = (ax + ay) + (az + aw);
                d += __shfl_xor(d, 1);
                d += __shfl_xor(d, 2);
                if (sub == 0) ep[p] = __expf(d * kTInv);
            }
        }
        __builtin_amdgcn_sched_barrier(0);
        asm volatile("s_waitcnt lgkmcnt(0)" ::: "memory");
        __builtin_amdgcn_s_barrier();
        __builtin_amdgcn_sched_barrier(0);

        // ---- rotate pipeline state ----
        sl0 = sn0; sl1 = sn1; sl2 = sn2; sl3 = sn3;
        carry = carryn;
        oA = oB; cA = cB; oB = oC; cB = cC;
    }
}

// ---------- fallback path (R2): separate gather + copy ----------

__global__ __launch_bounds__(256) void dots_kernel(
    const float* __restrict__ mem1, const float* __restrict__ mem2,
    const float* __restrict__ teacher, const float* __restrict__ student,
    const int* __restrict__ cidx,
    float* __restrict__ e2, float* __restrict__ e1)
{
    int gtid = blockIdx.x * 256 + threadIdx.x;
    int wave = gtid >> 6;
    int lane = threadIdx.x & 63;
    if (wave >= kNPair) return;
    int b = wave / kKC;
    long long row = (long long)cidx[wave] * kD;
    const float2 m1 = *reinterpret_cast<const float2*>(mem1 + row + lane * 2);
    const float2 m2 = *reinterpret_cast<const float2*>(mem2 + row + lane * 2);
    const float2 tv = *reinterpret_cast<const float2*>(teacher + b * kD + lane * 2);
    const float2 sv = *reinterpret_cast<const float2*>(student + b * kD + lane * 2);
    float d1 = m1.x * tv.x + m1.y * tv.y;
    float d2 = m2.x * sv.x + m2.y * sv.y;
    #pragma unroll
    for (int off = 32; off > 0; off >>= 1) {
        d1 += __shfl_xor(d1, off);
        d2 += __shfl_xor(d2, off);
    }
    if (lane == 0) {
        e2[wave] = __expf(d1 * kTInv);
        e1[wave] = __expf(d2 * kTInv);
    }
}

__global__ __launch_bounds__(256) void copy_kernel(
    const float* __restrict__ mem1, const float* __restrict__ mem2,
    float* __restrict__ out)
{
    const long long NV4 = (kTot + 1) / 4;
    const long long KS  = kM / 4;
    const float4* m1v = reinterpret_cast<const float4*>(mem1);
    const float4* m2v = reinterpret_cast<const float4*>(mem2);
    float4* ov = reinterpret_cast<float4*>(out);
    long long stride = (long long)gridDim.x * 256;
    for (long long k = (long long)blockIdx.x * 256 + threadIdx.x; k < NV4; k += stride) {
        if (k == 0) {
            out[1] = mem1[0]; out[2] = mem1[1]; out[3] = mem1[2];
            out[kTot] = mem2[kM - 1];
            continue;
        }
        float4 r;
        if (k < KS) {
            float4 a = m1v[k - 1];
            float4 b = m1v[k];
            r = make_float4(a.w, b.x, b.y, b.z);
        } else if (k == KS) {
            r = make_float4(mem1[kM - 1], mem2[0], mem2[1], mem2[2]);
        } else {
            float4 a = m2v[k - KS - 1];
            float4 b = m2v[k - KS];
            r = make_float4(a.w, b.x, b.y, b.z);
        }
        ov[k] = r;
    }
}

// ---------- loss chain ----------

__global__ __launch_bounds__(256) void sums_kernel(
    const float* __restrict__ e2, const float* __restrict__ e1,
    float* __restrict__ p2, float* __restrict__ p1)
{
    __shared__ float s2[256], s1[256];
    float a2 = 0.f, a1 = 0.f;
    for (int i = blockIdx.x * 256 + threadIdx.x; i < kNPair; i += 256 * kRB) {
        a2 += e2[i];
        a1 += e1[i];
    }
    s2[threadIdx.x] = a2; s1[threadIdx.x] = a1;
    __syncthreads();
    for (int st = 128; st > 0; st >>= 1) {
        if ((int)threadIdx.x < st) {
            s2[threadIdx.x] += s2[threadIdx.x + st];
            s1[threadIdx.x] += s1[threadIdx.x + st];
        }
        __syncthreads();
    }
    if (threadIdx.x == 0) { p2[blockIdx.x] = s2[0]; p1[blockIdx.x] = s1[0]; }
}

__global__ __launch_bounds__(256) void z_kernel(
    const float* __restrict__ p2, const float* __restrict__ p1, float* __restrict__ z)
{
    __shared__ float s2[256], s1[256];
    s2[threadIdx.x] = p2[threadIdx.x];
    s1[threadIdx.x] = p1[threadIdx.x];
    __syncthreads();
    for (int st = 128; st > 0; st >>= 1) {
        if ((int)threadIdx.x < st) {
            s2[threadIdx.x] += s2[threadIdx.x + st];
            s1[threadIdx.x] += s1[threadIdx.x + st];
        }
        __syncthreads();
    }
    if (threadIdx.x == 0) {
        const float scale = (float)kN / (float)kNPair;
        z[0] = s2[0] * scale;   // z_v2
        z[1] = s1[0] * scale;   // z_v1
    }
}

__global__ __launch_bounds__(256) void lossp_kernel(
    const float* __restrict__ e2, const float* __restrict__ e1,
    const float* __restrict__ z, float* __restrict__ lp)
{
    const float mpn = 2048.0f / 500000.0f;
    const float noise = mpn + 1e-7f;
    const float iz2 = 1.0f / z[0];
    const float iz1 = 1.0f / z[1];
    float acc = 0.f;
    for (int i = blockIdx.x * 256 + threadIdx.x; i < kNPair; i += 256 * kRB) {
        int k = i % kKC;
        float x2 = e2[i] * iz2;
        float x1 = e1[i] * iz1;
        if (k == 0) {
            acc += __logf(x2 / (x2 + noise)) + __logf(x1 / (x1 + noise));
        } else {
            acc += __logf(mpn / (x2 + noise)) + __logf(mpn / (x1 + noise));
        }
    }
    __shared__ float s[256];
    s[threadIdx.x] = acc;
    __syncthreads();
    for (int st = 128; st > 0; st >>= 1) {
        if ((int)threadIdx.x < st) s[threadIdx.x] += s[threadIdx.x + st];
        __syncthreads();
    }
    if (threadIdx.x == 0) lp[blockIdx.x] = s[0];
}

__global__ __launch_bounds__(256) void final_kernel(
    const float* __restrict__ lp, float* __restrict__ out)
{
    __shared__ float s[256];
    s[threadIdx.x] = lp[threadIdx.x];
    __syncthreads();
    for (int st = 128; st > 0; st >>= 1) {
        if ((int)threadIdx.x < st) s[threadIdx.x] += s[threadIdx.x + st];
        __syncthreads();
    }
    if (threadIdx.x == 0) out[0] = -s[0] / (float)kB;
}

// ---------- momentum update of the 256 pos rows ----------

__global__ __launch_bounds__(64) void update_kernel(
    const float* __restrict__ mem1, const float* __restrict__ mem2,
    const float* __restrict__ student, const float* __restrict__ teacher,
    const int* __restrict__ pos_idx,
    float* __restrict__ out1, float* __restrict__ out2)
{
    int b = blockIdx.x;
    int lane = threadIdx.x;
    int p = pos_idx[b];
    for (int b2 = b + 1; b2 < kB; ++b2)
        if (pos_idx[b2] == p) return;   // a later write wins
    long long row = (long long)p * kD;
    float2 m1 = *reinterpret_cast<const float2*>(mem1 + row + lane * 2);
    float2 m2 = *reinterpret_cast<const float2*>(mem2 + row + lane * 2);
    float2 sv = *reinterpret_cast<const float2*>(student + b * kD + lane * 2);
    float2 tv = *reinterpret_cast<const float2*>(teacher + b * kD + lane * 2);
    float2 l1 = make_float2(m1.x * kMom + sv.x * (1.f - kMom),
                            m1.y * kMom + sv.y * (1.f - kMom));
    float2 l2 = make_float2(m2.x * kMom + tv.x * (1.f - kMom),
                            m2.y * kMom + tv.y * (1.f - kMom));
    float n1 = l1.x * l1.x + l1.y * l1.y;
    float n2 = l2.x * l2.x + l2.y * l2.y;
    #pragma unroll
    for (int off = 32; off > 0; off >>= 1) {
        n1 += __shfl_xor(n1, off);
        n2 += __shfl_xor(n2, off);
    }
    float i1 = 1.0f / sqrtf(n1);
    float i2 = 1.0f / sqrtf(n2);
    out1[row + lane * 2]     = l1.x * i1;
    out1[row + lane * 2 + 1] = l1.y * i1;
    out2[row + lane * 2]     = l2.x * i2;
    out2[row + lane * 2 + 1] = l2.y * i2;
}

extern "C" void kernel_launch(void* const* d_in, const int* in_sizes, int n_in,
                              void* d_out, int out_size, void* d_ws, size_t ws_size,
                              hipStream_t stream) {
    const float* student = (const float*)d_in[0];
    const float* teacher = (const float*)d_in[1];
    const float* mem1    = (const float*)d_in[2];
    const float* mem2    = (const float*)d_in[3];
    const int*   pos_idx = (const int*)d_in[4];
    const int*   cidx    = (const int*)d_in[5];

    float* out  = (float*)d_out;
    float* out1 = out + 1;
    float* out2 = out + 1 + kM;

    // ws layout (sorted64 right after e-arrays: 8B-aligned offset)
    float* ws = (float*)d_ws;
    float* e2 = ws;                            // kNPair
    float* e1 = e2 + kNPair;                   // kNPair
    long long* sorted64 = (long long*)(e1 + kNPair);   // kNPair (8B each)
    float* p2 = (float*)(sorted64 + kNPair);   // kRB
    float* p1 = p2 + kRB;                      // kRB
    float* zz = p1 + kRB;                      // 2
    float* lp = zz + 2;                        // kRB
    int*   A    = (int*)(lp + kRB);            // kN counts
    int*   cur  = A + kN;                      // kN scatter cursor
    int*   offs = cur + kN;                    // kN + 1
    int*   bsum = offs + kN + 1;               // kNB1
    int*   bpre = bsum + kNB1;                 // kNB1
    size_t need = (size_t)((char*)(bpre + kNB1) - (char*)d_ws);

    if (ws_size >= need) {
        // CSR setup (A and cur zeroed in one async memset)
        hipMemsetAsync(A, 0, 2 * (size_t)kN * sizeof(int), stream);
        hist_kernel<<<(kNPair + 255) / 256, 256, 0, stream>>>(cidx, A);
        scan1_kernel<<<kNB1, 256, 0, stream>>>(A, bsum);
        scan2_kernel<<<1, 256, 0, stream>>>(bsum, bpre, offs);
        scan3_kernel<<<kNB1, 256, 0, stream>>>(A, bpre, offs);
        scatter_kernel<<<(kNPair + 255) / 256, 256, 0, stream>>>(cidx, offs, cur, sorted64);
        // fused tiled copy + dots, full prefetch pipeline
        fused9_kernel<<<kGrid9, 256, 0, stream>>>(mem1, mem2, teacher, student,
                                                  offs, sorted64, out, e2, e1);
    } else {
        // fallback: R2 path
        int nblocks = (kNPair + 3) / 4;
        dots_kernel<<<nblocks, 256, 0, stream>>>(mem1, mem2, teacher, student, cidx, e2, e1);
        copy_kernel<<<2048, 256, 0, stream>>>(mem1, mem2, out);
    }

    sums_kernel<<<kRB, 256, 0, stream>>>(e2, e1, p2, p1);
    z_kernel<<<1, 256, 0, stream>>>(p2, p1, zz);
    lossp_kernel<<<kRB, 256, 0, stream>>>(e2, e1, zz, lp);
    final_kernel<<<1, 256, 0, stream>>>(lp, out);
    update_kernel<<<kB, 64, 0, stream>>>(mem1, mem2, student, teacher, pos_idx, out1, out2);
}